// Round 10
// baseline (192.692 us; speedup 1.0000x reference)
//
#include <hip/hip_runtime.h>
#include <math.h>

// Problem constants
#define BQ 64
#define NOBJ 5
#define CIN 3
#define IMG_H 64
#define IMG_W 96
#define OH 32
#define OW 48
#define NPAIR 25
#define PP 4
#define CONV_OUT 32

// Tiling: block = (src, b, rowgroup of 2 output rows); 512 threads = 8 waves.
// LDS = TWO single-row buffers (15.4 KB each, 30.7 KB total like r6).
// Row 1 is register-prefetched during row-0 compute (T14 async-stage).
#define NRG 16                          // 32 output rows / 2
#define RPOS 48                         // positions per output row
#define ROW_U32 (NOBJ * RPOS * 16)      // 3840 u32 = 15.4 KB per row buffer
#define ROWU (NOBJ * RPOS * 4)          // 960 8-elem units per row

#define NPRED (2 * 1600 * PP)           // 12800
#define S_FLOATS (2 * BQ * NPAIR * PP)  // 12800 accumulator slots

typedef __fp16   h2 __attribute__((ext_vector_type(2)));     // cvt_pkrtz result type
typedef _Float16 half8 __attribute__((ext_vector_type(8)));  // MFMA A/B operand
typedef float    float4_ __attribute__((ext_vector_type(4)));
typedef unsigned int uint4_ __attribute__((ext_vector_type(4)));

// Fused: conv + pair-combine + cross-block reduction + sigmoid epilogue.
//
// HISTORY (keep):
//  r2/r3: __launch_bounds__(512,4) acts as a 64-VGPR cap -> 448 MB spill.
//  r4/r5: reduce-MFMA epilogue (4 regs/pair x 25) spills or kills occupancy.
//  r7:    SERIALIZED 2-phase staging regressed (no overlap, occ 50->37.5).
//  r8:    __threadfence() x2 -> L2 writeback storm, 475 us. Removed r9 (79 us):
//         all cross-block comms are device-scope atomics; syncthreads' implied
//         vmcnt(0) orders S-adds before the cnt RMW; reader uses agent-scope
//         atomic loads.
//  r9:    fused total == two-kernel total -> ~75 us of dur_us is fixed harness
//         overhead; only the conv kernel is controllable.
//  r10:   THIS: async-stage pipeline. Stage row0 -> barrier -> issue row1
//         loads to regs -> compute row0 -> write row1 to bufB -> barrier ->
//         compute row1. Hides scattered-gather HBM latency under MFMA+combine.
__global__ __launch_bounds__(512) void conv_pair_fused(
    const float* __restrict__ state,
    const float* __restrict__ state_next,
    const float* __restrict__ conv_w,
    const float* __restrict__ conv_b,
    const float* __restrict__ w2,
    const float* __restrict__ b2,
    const float* __restrict__ temp,
    float* __restrict__ S,              // [2][64][25][4] accumulators (zeroed)
    unsigned int* __restrict__ cnt,     // [2][64] arrival counters (zeroed)
    float* __restrict__ out)
{
    __shared__ __align__(16) unsigned int sX32[2 * ROW_U32];   // 30.7 KB
    __shared__ int islast;

    const int tid = threadIdx.x;
    const int rg  = blockIdx.x;     // 0..15
    const int b   = blockIdx.y;     // 0..63
    const int src = blockIdx.z;     // 0..1

    const float* g = (src == 0 ? state : state_next)
                   + (size_t)b * NOBJ * CIN * IMG_H * IMG_W;
    const int R0 = rg * 4;          // first input row of this rowgroup

    // ---- adj mask from src==1 blocks (independent; pre-barrier) ----
    if (src == 1 && tid < 100) {
        int a  = (rg + NRG * b) * 100 + tid;     // 1024 blocks x 100 = 102400
        int bb = a / 1600;
        int t  = a - bb * 1600;
        out[NPRED + a] = (t / NPAIR == bb) ? 1.0f : 0.0f;
    }

    const int wave = tid >> 6;      // 0..7 -> mt
    const int lane = tid & 63;
    const int quad = lane >> 4;
    const int ocl  = lane & 15;

    const int mt  = wave;
    const int p   = mt >> 1;
    const int row = mt * 16 + ocl;  // this lane's conv_w row (oc)

    // ---- per-lane weights as f16 (global loads issue early) ----
    half8 wa, wb;
    #pragma unroll
    for (int j = 0; j < 8; ++j) {
        int k = quad * 8 + j;
        float va = 0.f, vb = 0.f;
        if (k < 27) {
            va = conv_w[row * 54 + k];
            vb = conv_w[row * 54 + 27 + k];
        } else if (k == 27) {
            va = conv_b[row];       // bias pairs with 1.0 lane in X
        }
        wa[j] = (_Float16)va;
        wb[j] = (_Float16)vb;
    }
    h2 w2h01, w2h23;
    {
        const float* wp = w2 + p * CONV_OUT + (mt & 1) * 16 + quad * 4;
        w2h01 = __builtin_amdgcn_cvt_pkrtz(wp[0], wp[1]);
        w2h23 = __builtin_amdgcn_cvt_pkrtz(wp[2], wp[3]);
    }

    // ---- im2col k-decode tables (subk = tid&3, invariant) ----
    const int subk = tid & 3;
    int koff[8], khv[8], kwv[8];
    float padf[8];
    bool kval[8];
    #pragma unroll
    for (int j = 0; j < 8; ++j) {
        int k = subk * 8 + j;
        if (k < 27) {
            int ci = k / 9;
            int r9 = k - ci * 9;
            int kh = r9 / 3;
            int kw = r9 - kh * 3;
            koff[j] = ci * (IMG_H * IMG_W) + kh * IMG_W + kw;
            khv[j] = kh; kwv[j] = kw; kval[j] = true; padf[j] = 0.f;
        } else {
            koff[j] = 0; khv[j] = 0; kwv[j] = 0; kval[j] = false;
            padf[j] = (k == 27) ? 1.0f : 0.f;
        }
    }

    // ---- stage row 0 into buffer A (load + cvt + swizzled write) ----
    // unit u = obj*192 + pl*4 + subk; 960 units, 2 strided iterations.
    // 16B chunk XOR-swizzle (pos>>1)&3 verified r2-r9: bank conflicts = 0.
    {
        const int gr0 = R0;
        for (int u = tid; u < ROWU; u += 512) {
            int pl  = (u >> 2) % RPOS;
            int obj = u / (RPOS * 4);
            int gc0 = 2 * pl;
            const float* gp = g + obj * (CIN * IMG_H * IMG_W) + gr0 * IMG_W + gc0;
            float fv[8];
            #pragma unroll
            for (int j = 0; j < 8; ++j) {
                float v = padf[j];
                if (kval[j] && (gr0 + khv[j] < IMG_H) && (gc0 + kwv[j] < IMG_W))
                    v = gp[koff[j]];
                fv[j] = v;
            }
            uint4_ w4;
            w4.x = __builtin_bit_cast(unsigned int, __builtin_amdgcn_cvt_pkrtz(fv[0], fv[1]));
            w4.y = __builtin_bit_cast(unsigned int, __builtin_amdgcn_cvt_pkrtz(fv[2], fv[3]));
            w4.z = __builtin_bit_cast(unsigned int, __builtin_amdgcn_cvt_pkrtz(fv[4], fv[5]));
            w4.w = __builtin_bit_cast(unsigned int, __builtin_amdgcn_cvt_pkrtz(fv[6], fv[7]));
            int swk = subk ^ ((pl >> 1) & 3);
            *(uint4_*)&sX32[(size_t)(obj * (RPOS * 16) + pl * 16 + swk * 4)] = w4;
        }
    }

    __syncthreads();

    // ---- issue row-1 global loads into registers NOW (latency hides under
    //      row-0 compute). Two statically-unrolled units per thread.
    float fvA[8], fvB[8];
    bool hasB;
    {
        const int gr1 = R0 + 2;
        {   // unit u0 = tid (always < 960)
            int u   = tid;
            int pl  = (u >> 2) % RPOS;
            int obj = u / (RPOS * 4);
            int gc0 = 2 * pl;
            const float* gp = g + obj * (CIN * IMG_H * IMG_W) + gr1 * IMG_W + gc0;
            #pragma unroll
            for (int j = 0; j < 8; ++j) {
                float v = padf[j];
                if (kval[j] && (gr1 + khv[j] < IMG_H) && (gc0 + kwv[j] < IMG_W))
                    v = gp[koff[j]];
                fvA[j] = v;
            }
        }
        hasB = (tid + 512 < ROWU);      // tids 0..447
        if (hasB) {
            int u   = tid + 512;
            int pl  = (u >> 2) % RPOS;
            int obj = u / (RPOS * 4);
            int gc0 = 2 * pl;
            const float* gp = g + obj * (CIN * IMG_H * IMG_W) + gr1 * IMG_W + gc0;
            #pragma unroll
            for (int j = 0; j < 8; ++j) {
                float v = padf[j];
                if (kval[j] && (gr1 + khv[j] < IMG_H) && (gc0 + kwv[j] < IMG_W))
                    v = gp[koff[j]];
                fvB[j] = v;
            }
        } else {
            #pragma unroll
            for (int j = 0; j < 8; ++j) fvB[j] = 0.f;
        }
    }

    const float4_ zero4 = {0.f, 0.f, 0.f, 0.f};
    const h2 hz = {(__fp16)0.f, (__fp16)0.f};

    float acc[NPAIR];
    #pragma unroll
    for (int q = 0; q < NPAIR; ++q) acc[q] = 0.f;

    // ---- compute macro over one row buffer (3 col-tiles of 16) ----
    #define COMPUTE_ROW(RBASE)                                                   \
    _Pragma("unroll")                                                            \
    for (int nt3 = 0; nt3 < 3; ++nt3) {                                          \
        const int pos = nt3 * 16 + ocl;                                          \
        const int sw  = (pos >> 1) & 3;                                          \
        const int sbase = (RBASE) + pos * 16 + ((quad ^ sw) << 2);               \
        half8 xf[NOBJ];                                                          \
        h2 ah01[NOBJ], ah23[NOBJ];                                               \
        _Pragma("unroll")                                                        \
        for (int obj = 0; obj < NOBJ; ++obj) {                                   \
            xf[obj] = *(const half8*)&sX32[sbase + obj * (RPOS * 16)];           \
            float4_ a = __builtin_amdgcn_mfma_f32_16x16x32_f16(wa, xf[obj], zero4, 0, 0, 0); \
            ah01[obj] = __builtin_amdgcn_cvt_pkrtz(a[0], a[1]);                  \
            ah23[obj] = __builtin_amdgcn_cvt_pkrtz(a[2], a[3]);                  \
        }                                                                        \
        _Pragma("unroll")                                                        \
        for (int jo = 0; jo < NOBJ; ++jo) {                                      \
            float4_ bq = __builtin_amdgcn_mfma_f32_16x16x32_f16(wb, xf[jo], zero4, 0, 0, 0); \
            h2 bh01 = __builtin_amdgcn_cvt_pkrtz(bq[0], bq[1]);                  \
            h2 bh23 = __builtin_amdgcn_cvt_pkrtz(bq[2], bq[3]);                  \
            _Pragma("unroll")                                                    \
            for (int i = 0; i < NOBJ; ++i) {                                     \
                h2 s0 = ah01[i] + bh01;                                          \
                h2 s1 = ah23[i] + bh23;                                          \
                s0 = __builtin_elementwise_max(s0, hz);                          \
                s1 = __builtin_elementwise_max(s1, hz);                          \
                float t0 = __builtin_amdgcn_fdot2(s0, w2h01, acc[i * NOBJ + jo], false); \
                acc[i * NOBJ + jo] = __builtin_amdgcn_fdot2(s1, w2h23, t0, false);       \
            }                                                                    \
        }                                                                        \
    }

    COMPUTE_ROW(0)                      // row 0 from buffer A

    // ---- write prefetched row 1 into buffer B (no barrier needed before:
    //      buffer B untouched; loads complete via register dependencies) ----
    {
        {
            int u   = tid;
            int pl  = (u >> 2) % RPOS;
            int obj = u / (RPOS * 4);
            uint4_ w4;
            w4.x = __builtin_bit_cast(unsigned int, __builtin_amdgcn_cvt_pkrtz(fvA[0], fvA[1]));
            w4.y = __builtin_bit_cast(unsigned int, __builtin_amdgcn_cvt_pkrtz(fvA[2], fvA[3]));
            w4.z = __builtin_bit_cast(unsigned int, __builtin_amdgcn_cvt_pkrtz(fvA[4], fvA[5]));
            w4.w = __builtin_bit_cast(unsigned int, __builtin_amdgcn_cvt_pkrtz(fvA[6], fvA[7]));
            int swk = subk ^ ((pl >> 1) & 3);
            *(uint4_*)&sX32[(size_t)(ROW_U32 + obj * (RPOS * 16) + pl * 16 + swk * 4)] = w4;
        }
        if (hasB) {
            int u   = tid + 512;
            int pl  = (u >> 2) % RPOS;
            int obj = u / (RPOS * 4);
            uint4_ w4;
            w4.x = __builtin_bit_cast(unsigned int, __builtin_amdgcn_cvt_pkrtz(fvB[0], fvB[1]));
            w4.y = __builtin_bit_cast(unsigned int, __builtin_amdgcn_cvt_pkrtz(fvB[2], fvB[3]));
            w4.z = __builtin_bit_cast(unsigned int, __builtin_amdgcn_cvt_pkrtz(fvB[4], fvB[5]));
            w4.w = __builtin_bit_cast(unsigned int, __builtin_amdgcn_cvt_pkrtz(fvB[6], fvB[7]));
            int swk = subk ^ ((pl >> 1) & 3);
            *(uint4_*)&sX32[(size_t)(ROW_U32 + obj * (RPOS * 16) + pl * 16 + swk * 4)] = w4;
        }
    }

    __syncthreads();

    COMPUTE_ROW(ROW_U32)                // row 1 from buffer B
    #undef COMPUTE_ROW

    // ---- wave-reduce each pair across 64 lanes ----
    float myv = 0.f;
    #pragma unroll
    for (int q = 0; q < NPAIR; ++q) {
        float rr = acc[q];
        #pragma unroll
        for (int off = 32; off > 0; off >>= 1)
            rr += __shfl_xor(rr, off, 64);
        if (lane == q) myv = rr;
    }

    // ---- cross-block accumulate: 16 rg-blocks x 2 mt-waves -> S[src][b][pair][p]
    const size_t sbidx = ((size_t)src * BQ + b);
    if (lane < NPAIR)
        atomicAdd(&S[(sbidx * NPAIR + lane) * PP + p], myv);

    // syncthreads' implied vmcnt(0): every thread's S-atomic completed at the
    // coherent point before any thread proceeds (verified r9: fence-free OK).
    __syncthreads();
    if (tid == 0) {
        unsigned int old = atomicAdd(&cnt[sbidx], 1u);
        islast = (old == NRG - 1);
    }
    __syncthreads();

    // ---- last arriving block for this (src,b) finishes the 100 predicates ----
    if (islast && tid < NPAIR * PP) {
        int pair = tid >> 2;
        int pp   = tid & 3;
        float s = __hip_atomic_load(&S[(sbidx * NPAIR + pair) * PP + pp],
                                    __ATOMIC_RELAXED, __HIP_MEMORY_SCOPE_AGENT);
        float logit = s * (1.0f / (OH * OW)) + b2[pp];
        float x = logit / temp[0];
        out[(size_t)src * 6400 + ((size_t)b * NPAIR + pair) * PP + pp] =
            1.0f / (1.0f + expf(-x));
    }
}

extern "C" void kernel_launch(void* const* d_in, const int* in_sizes, int n_in,
                              void* d_out, int out_size, void* d_ws, size_t ws_size,
                              hipStream_t stream)
{
    const float* state      = (const float*)d_in[0];
    const float* state_next = (const float*)d_in[1];
    const float* conv_w     = (const float*)d_in[2];
    const float* conv_b     = (const float*)d_in[3];
    const float* w2         = (const float*)d_in[4];
    const float* b2         = (const float*)d_in[5];
    // d_in[6] = n_obj (always 5)
    const float* temp       = (const float*)d_in[7];

    float* out = (float*)d_out;
    float* S   = (float*)d_ws;                          // 12800 floats
    unsigned int* cnt = (unsigned int*)(S + S_FLOATS);  // 128 counters

    // zero accumulators + counters (capture-safe async memset, ~52 KB)
    hipMemsetAsync(d_ws, 0, (S_FLOATS + 2 * BQ) * sizeof(float), stream);

    dim3 grid1(NRG, BQ, 2);                 // 2048 blocks x 512 threads
    conv_pair_fused<<<grid1, 512, 0, stream>>>(state, state_next, conv_w, conv_b,
                                               w2, b2, temp, S, cnt, out);
}

// Round 11
// 182.106 us; speedup vs baseline: 1.0581x; 1.0581x over previous
//
#include <hip/hip_runtime.h>
#include <math.h>

// Problem constants
#define BQ 64
#define NOBJ 5
#define CIN 3
#define IMG_H 64
#define IMG_W 96
#define OH 32
#define OW 48
#define NPAIR 25
#define PP 4
#define CONV_OUT 32

// Tiling: block = (src, b, rowgroup of 2 output rows); 256 threads = 4 waves.
// Each wave handles mt = wave and wave+4 sequentially (weights reloaded
// between halves to stay under the 64-VGPR / 8-waves-per-SIMD cliff).
// 30.7 KB LDS -> up to 5 blocks/CU co-resident (vs 2 with 512-thr blocks):
// independent barrier domains let one block's staging overlap others' compute.
#define NRG 16                          // 32 output rows / 2
#define NPOS 96                         // 2 output rows x 48 cols
#define XK 32                           // padded K (27 real + bias + zeros)
#define X_U32 (NOBJ * NPOS * XK / 2)    // 7680 u32 = 30.7 KB (f16 im2col)
#define X_UNITS (NOBJ * NPOS * 4)       // 1920 8-elem units

#define NPRED (2 * 1600 * PP)           // 12800
#define S_FLOATS (2 * BQ * NPAIR * PP)  // 12800 accumulator slots

typedef __fp16   h2 __attribute__((ext_vector_type(2)));     // cvt_pkrtz result type
typedef _Float16 half8 __attribute__((ext_vector_type(8)));  // MFMA A/B operand
typedef float    float4_ __attribute__((ext_vector_type(4)));
typedef unsigned int uint4_ __attribute__((ext_vector_type(4)));

// HISTORY (keep):
//  r2/r3:  __launch_bounds__(512,4) == 64-VGPR cap -> 448 MB scratch spill.
//  r4/r5:  reduce-MFMA epilogue (4 regs/pair x 25) spills or kills occupancy.
//  r7:     serialized 2-phase staging regressed (occ 50->37.5).
//  r8/r9:  per-thread __threadfence = L2 writeback storm (475 us); removed ->
//          79 us. Cross-block comms via device-scope atomics only; syncthreads'
//          implied vmcnt(0) orders S-adds before the cnt RMW.
//  r9:     fused total == two-kernel total -> ~75 us of dur_us is fixed
//          harness overhead; only this kernel is controllable.
//  r10:    reg-prefetch pipeline: VGPR 40->84 crosses the 64-VGPR cliff
//          (8->4 waves/SIMD), occ 22%, conv 118 us. REFUTED.
//  r11:    THIS: repack into 256-thr blocks, 2 mt per wave. Same work, same
//          VGPR class, 5 independent blocks/CU for cross-block latency cover.
__global__ __launch_bounds__(256) void conv_pair_fused(
    const float* __restrict__ state,
    const float* __restrict__ state_next,
    const float* __restrict__ conv_w,
    const float* __restrict__ conv_b,
    const float* __restrict__ w2,
    const float* __restrict__ b2,
    const float* __restrict__ temp,
    float* __restrict__ S,              // [2][64][25][4] accumulators (zeroed)
    unsigned int* __restrict__ cnt,     // [2][64] arrival counters (zeroed)
    float* __restrict__ out)
{
    __shared__ __align__(16) unsigned int sX32[X_U32];   // 30.7 KB f16 im2col
    __shared__ int islast;

    const int tid = threadIdx.x;
    const int rg  = blockIdx.x;     // 0..15
    const int b   = blockIdx.y;     // 0..63
    const int src = blockIdx.z;     // 0..1

    const float* g = (src == 0 ? state : state_next)
                   + (size_t)b * NOBJ * CIN * IMG_H * IMG_W;
    const int R0 = rg * 4;          // first input row of this rowgroup

    // ---- adj mask from src==1 blocks (independent; pre-barrier) ----
    if (src == 1 && tid < 100) {
        int a  = (rg + NRG * b) * 100 + tid;     // 1024 blocks x 100 = 102400
        int bb = a / 1600;
        int t  = a - bb * 1600;
        out[NPRED + a] = (t / NPAIR == bb) ? 1.0f : 0.0f;
    }

    const int wave = tid >> 6;      // 0..3
    const int lane = tid & 63;
    const int quad = lane >> 4;
    const int ocl  = lane & 15;

    // ---- build f16 im2col sX[obj][pos][k] directly from global.
    // unit u = obj*384 + pos*4 + subk; subk = tid&3 invariant under += 256.
    // k = subk*8+j; k==27 -> 1.0 (bias partner), k>27 -> 0, OOB -> 0.
    // 16B chunk XOR-swizzle (pos>>1)&3 verified r2-r10: bank conflicts = 0.
    {
        const int subk = tid & 3;
        int koff[8], khv[8], kwv[8];
        float padf[8];
        bool kval[8];
        #pragma unroll
        for (int j = 0; j < 8; ++j) {
            int k = subk * 8 + j;
            if (k < 27) {
                int ci = k / 9;
                int r9 = k - ci * 9;
                int kh = r9 / 3;
                int kw = r9 - kh * 3;
                koff[j] = ci * (IMG_H * IMG_W) + kh * IMG_W + kw;
                khv[j] = kh; kwv[j] = kw; kval[j] = true; padf[j] = 0.f;
            } else {
                koff[j] = 0; khv[j] = 0; kwv[j] = 0; kval[j] = false;
                padf[j] = (k == 27) ? 1.0f : 0.f;
            }
        }
        for (int u = tid; u < X_UNITS; u += 256) {
            int pl  = (u >> 2) % NPOS;
            int obj = u / (NPOS * 4);
            int rl  = (pl >= 48) ? 1 : 0;
            int pc  = pl - rl * 48;
            int gr0 = R0 + 2 * rl;
            int gc0 = 2 * pc;
            const float* gp = g + obj * (CIN * IMG_H * IMG_W) + gr0 * IMG_W + gc0;
            float fv[8];
            #pragma unroll
            for (int j = 0; j < 8; ++j) {
                float v = padf[j];
                if (kval[j] && (gr0 + khv[j] < IMG_H) && (gc0 + kwv[j] < IMG_W))
                    v = gp[koff[j]];
                fv[j] = v;
            }
            uint4_ w4;
            w4.x = __builtin_bit_cast(unsigned int, __builtin_amdgcn_cvt_pkrtz(fv[0], fv[1]));
            w4.y = __builtin_bit_cast(unsigned int, __builtin_amdgcn_cvt_pkrtz(fv[2], fv[3]));
            w4.z = __builtin_bit_cast(unsigned int, __builtin_amdgcn_cvt_pkrtz(fv[4], fv[5]));
            w4.w = __builtin_bit_cast(unsigned int, __builtin_amdgcn_cvt_pkrtz(fv[6], fv[7]));
            int swk = subk ^ ((pl >> 1) & 3);
            *(uint4_*)&sX32[(size_t)(obj * (NPOS * 16) + pl * 16 + swk * 4)] = w4;
        }
    }

    __syncthreads();

    const float4_ zero4 = {0.f, 0.f, 0.f, 0.f};
    const h2 hz = {(__fp16)0.f, (__fp16)0.f};
    const size_t sbidx = ((size_t)src * BQ + b);

    // ---- two oc-tile halves per wave: mt = wave, wave+4 ----
    for (int half = 0; half < 2; ++half) {
        const int mt  = wave + 4 * half;
        const int p   = mt >> 1;
        const int row = mt * 16 + ocl;  // this lane's conv_w row (oc)

        half8 wa, wb;
        #pragma unroll
        for (int j = 0; j < 8; ++j) {
            int k = quad * 8 + j;
            float va = 0.f, vb = 0.f;
            if (k < 27) {
                va = conv_w[row * 54 + k];
                vb = conv_w[row * 54 + 27 + k];
            } else if (k == 27) {
                va = conv_b[row];       // bias pairs with 1.0 lane in X
            }
            wa[j] = (_Float16)va;
            wb[j] = (_Float16)vb;
        }
        h2 w2h01, w2h23;
        {
            const float* wp = w2 + p * CONV_OUT + (mt & 1) * 16 + quad * 4;
            w2h01 = __builtin_amdgcn_cvt_pkrtz(wp[0], wp[1]);
            w2h23 = __builtin_amdgcn_cvt_pkrtz(wp[2], wp[3]);
        }

        float acc[NPAIR];
        #pragma unroll
        for (int q = 0; q < NPAIR; ++q) acc[q] = 0.f;

        #pragma unroll
        for (int nt = 0; nt < 6; ++nt) {    // 2 rows x 3 col-tiles of 16
            const int rl  = nt / 3;
            const int c0  = (nt - rl * 3) * 16;
            const int pos = rl * 48 + c0 + ocl;
            const int sw  = (pos >> 1) & 3;
            const int sbase = pos * 16 + ((quad ^ sw) << 2);

            half8 xf[NOBJ];
            h2 ah01[NOBJ], ah23[NOBJ];
            #pragma unroll
            for (int obj = 0; obj < NOBJ; ++obj) {
                xf[obj] = *(const half8*)&sX32[sbase + obj * (NPOS * 16)];
                float4_ a = __builtin_amdgcn_mfma_f32_16x16x32_f16(wa, xf[obj], zero4, 0, 0, 0);
                ah01[obj] = __builtin_amdgcn_cvt_pkrtz(a[0], a[1]);
                ah23[obj] = __builtin_amdgcn_cvt_pkrtz(a[2], a[3]);
            }

            #pragma unroll
            for (int jo = 0; jo < NOBJ; ++jo) {
                float4_ bq = __builtin_amdgcn_mfma_f32_16x16x32_f16(wb, xf[jo], zero4, 0, 0, 0);
                h2 bh01 = __builtin_amdgcn_cvt_pkrtz(bq[0], bq[1]);
                h2 bh23 = __builtin_amdgcn_cvt_pkrtz(bq[2], bq[3]);
                #pragma unroll
                for (int i = 0; i < NOBJ; ++i) {
                    h2 s0 = ah01[i] + bh01;                        // v_pk_add_f16
                    h2 s1 = ah23[i] + bh23;
                    s0 = __builtin_elementwise_max(s0, hz);        // v_pk_max_f16
                    s1 = __builtin_elementwise_max(s1, hz);
                    float t0 = __builtin_amdgcn_fdot2(s0, w2h01, acc[i * NOBJ + jo], false);
                    acc[i * NOBJ + jo] = __builtin_amdgcn_fdot2(s1, w2h23, t0, false);
                }
            }
        }

        // ---- wave-reduce each pair across 64 lanes ----
        float myv = 0.f;
        #pragma unroll
        for (int q = 0; q < NPAIR; ++q) {
            float rr = acc[q];
            #pragma unroll
            for (int off = 32; off > 0; off >>= 1)
                rr += __shfl_xor(rr, off, 64);
            if (lane == q) myv = rr;
        }

        // device-scope atomics complete at the coherent point (fence-free, r9)
        if (lane < NPAIR)
            atomicAdd(&S[(sbidx * NPAIR + lane) * PP + p], myv);
    }

    // syncthreads' implied vmcnt(0): every thread's S-atomics completed at the
    // coherent point before any thread proceeds (verified r9).
    __syncthreads();
    if (tid == 0) {
        unsigned int old = atomicAdd(&cnt[sbidx], 1u);
        islast = (old == NRG - 1);
    }
    __syncthreads();

    // ---- last arriving block for this (src,b) finishes the 100 predicates ----
    if (islast && tid < NPAIR * PP) {
        int pair = tid >> 2;
        int pp   = tid & 3;
        float s = __hip_atomic_load(&S[(sbidx * NPAIR + pair) * PP + pp],
                                    __ATOMIC_RELAXED, __HIP_MEMORY_SCOPE_AGENT);
        float logit = s * (1.0f / (OH * OW)) + b2[pp];
        float x = logit / temp[0];
        out[(size_t)src * 6400 + ((size_t)b * NPAIR + pair) * PP + pp] =
            1.0f / (1.0f + expf(-x));
    }
}

extern "C" void kernel_launch(void* const* d_in, const int* in_sizes, int n_in,
                              void* d_out, int out_size, void* d_ws, size_t ws_size,
                              hipStream_t stream)
{
    const float* state      = (const float*)d_in[0];
    const float* state_next = (const float*)d_in[1];
    const float* conv_w     = (const float*)d_in[2];
    const float* conv_b     = (const float*)d_in[3];
    const float* w2         = (const float*)d_in[4];
    const float* b2         = (const float*)d_in[5];
    // d_in[6] = n_obj (always 5)
    const float* temp       = (const float*)d_in[7];

    float* out = (float*)d_out;
    float* S   = (float*)d_ws;                          // 12800 floats
    unsigned int* cnt = (unsigned int*)(S + S_FLOATS);  // 128 counters

    // zero accumulators + counters (capture-safe async memset, ~52 KB)
    hipMemsetAsync(d_ws, 0, (S_FLOATS + 2 * BQ) * sizeof(float), stream);

    dim3 grid1(NRG, BQ, 2);                 // 2048 blocks x 256 threads
    conv_pair_fused<<<grid1, 256, 0, stream>>>(state, state_next, conv_w, conv_b,
                                               w2, b2, temp, S, cnt, out);
}

// Round 12
// 152.357 us; speedup vs baseline: 1.2647x; 1.1953x over previous
//
#include <hip/hip_runtime.h>
#include <math.h>

// Problem constants
#define BQ 64
#define NOBJ 5
#define CIN 3
#define IMG_H 64
#define IMG_W 96
#define OH 32
#define OW 48
#define NPAIR 25
#define PP 4
#define CONV_OUT 32

// Tiling: each block = (src, b, rowgroup of 2 output rows); 512 threads = 8 waves
#define NRG 16                          // 32 output rows / 2
#define NPOS 96                         // 2 output rows x 48 cols
#define XK 32                           // padded K (27 real + bias + zeros)
#define X_U32 (NOBJ * NPOS * XK / 2)    // 7680 u32 = 30.7 KB (f16 im2col)
#define X_UNITS (NOBJ * NPOS * 4)       // 1920 8-elem units

#define NPRED (2 * 1600 * PP)           // 12800
#define ADJ_N (BQ * 1600)               // 102400

typedef __fp16   h2 __attribute__((ext_vector_type(2)));     // cvt_pkrtz result type
typedef _Float16 half8 __attribute__((ext_vector_type(8)));  // MFMA A/B operand
typedef float    float4_ __attribute__((ext_vector_type(4)));
typedef float    float2_ __attribute__((ext_vector_type(2)));
typedef unsigned int uint4_ __attribute__((ext_vector_type(4)));

// T[src][b][rg][pair][mt]; mt = 16-oc tile 0..7 (p = mt>>1). Fully written,
// no memset, no atomics. src==1 blocks also write the adj mask.
//
// HISTORY / refuted-structures ledger (keep):
//  r2/r3:  __launch_bounds__(512,4) == 64-VGPR cap here -> 448 MB scratch spill.
//  r4/r5:  reduce-MFMA epilogue (4 regs/pair x 25) spills or kills occupancy.
//  r7:     serialized one-row staging: occ 50->37.5, conv 84 us. REFUTED.
//  r8:     per-thread __threadfence -> L2 writeback storm (475 us).
//  r9:     fused-single-kernel total == two-kernel total (155 vs 152) -> ~75 us
//          of dur_us is fixed harness overhead; only conv is controllable.
//  r10:    reg-prefetch pipeline: VGPR 40->84 crosses 64-VGPR cliff, conv 118.
//  r11:    256-thr repack: compiler kept both mt-halves live, VGPR 108, conv 111.
//  => conv's VALU floor: pair-combine = 900 packed ops/wave ~= 50 us/CU VALU
//     time (r8/r9 invariant). This round: delete dead bounds-check VALU in the
//     staging gather (interior fast path) on the r6 base; everything else
//     byte-identical to the 152.3 us best.
__global__ __launch_bounds__(512) void conv_pair_mfma(
    const float* __restrict__ state,
    const float* __restrict__ state_next,
    const float* __restrict__ conv_w,
    const float* __restrict__ conv_b,
    const float* __restrict__ w2,
    float* __restrict__ T,
    float* __restrict__ out)
{
    __shared__ __align__(16) unsigned int sX32[X_U32];   // 30.7 KB f16 im2col

    const int tid = threadIdx.x;
    const int rg  = blockIdx.x;     // 0..15
    const int b   = blockIdx.y;     // 0..63
    const int src = blockIdx.z;     // 0..1

    const float* g = (src == 0 ? state : state_next)
                   + (size_t)b * NOBJ * CIN * IMG_H * IMG_W;
    const int R0 = rg * 4;          // first input row of this rowgroup

    // ---- adj mask from src==1 blocks (independent; pre-barrier) ----
    if (src == 1 && tid < 100) {
        int a  = (rg + NRG * b) * 100 + tid;     // 1024 blocks x 100 = 102400
        int bb = a / 1600;
        int t  = a - bb * 1600;
        out[NPRED + a] = (t / NPAIR == bb) ? 1.0f : 0.0f;
    }

    const int wave = tid >> 6;      // 0..7 -> mt
    const int lane = tid & 63;
    const int quad = lane >> 4;
    const int ocl  = lane & 15;

    const int mt  = wave;
    const int p   = mt >> 1;
    const int row = mt * 16 + ocl;  // this lane's conv_w row (oc)

    // ---- per-lane weights as f16 (global loads issue early, overlap staging)
    half8 wa, wb;
    #pragma unroll
    for (int j = 0; j < 8; ++j) {
        int k = quad * 8 + j;
        float va = 0.f, vb = 0.f;
        if (k < 27) {
            va = conv_w[row * 54 + k];
            vb = conv_w[row * 54 + 27 + k];
        } else if (k == 27) {
            va = conv_b[row];       // bias pairs with 1.0 lane in X
        }
        wa[j] = (_Float16)va;
        wb[j] = (_Float16)vb;
    }
    h2 w2h01, w2h23;
    {
        const float* wp = w2 + p * CONV_OUT + (mt & 1) * 16 + quad * 4;
        w2h01 = __builtin_amdgcn_cvt_pkrtz(wp[0], wp[1]);
        w2h23 = __builtin_amdgcn_cvt_pkrtz(wp[2], wp[3]);
    }

    // ---- build f16 im2col sX[obj][pos][k] directly from global.
    // unit u = obj*384 + pos*4 + subk; subk = tid&3 invariant under += 512.
    // k = subk*8+j; k==27 -> 1.0 (bias partner), k>27 -> 0, OOB -> 0.
    // 16B chunk XOR-swizzle (pos>>1)&3 (verified r2-r11: conflicts = 0).
    // r12: interior fast path — OOB is only possible when gr0+2 >= 64
    // (rg=15, rl=1) or gc0+2 >= 96 (pc=47); everywhere else the two
    // per-load address compares are dead VALU and are removed.
    {
        const int subk = tid & 3;
        int koff[8], khv[8], kwv[8];
        float padf[8];
        bool kval[8];
        #pragma unroll
        for (int j = 0; j < 8; ++j) {
            int k = subk * 8 + j;
            if (k < 27) {
                int ci = k / 9;
                int r9 = k - ci * 9;
                int kh = r9 / 3;
                int kw = r9 - kh * 3;
                koff[j] = ci * (IMG_H * IMG_W) + kh * IMG_W + kw;
                khv[j] = kh; kwv[j] = kw; kval[j] = true; padf[j] = 0.f;
            } else {
                koff[j] = 0; khv[j] = 0; kwv[j] = 0; kval[j] = false;
                padf[j] = (k == 27) ? 1.0f : 0.f;
            }
        }
        for (int u = tid; u < X_UNITS; u += 512) {
            int pl  = (u >> 2) % NPOS;
            int obj = u / (NPOS * 4);
            int rl  = (pl >= 48) ? 1 : 0;
            int pc  = pl - rl * 48;
            int gr0 = R0 + 2 * rl;
            int gc0 = 2 * pc;
            const float* gp = g + obj * (CIN * IMG_H * IMG_W) + gr0 * IMG_W + gc0;
            float fv[8];
            if (gr0 + 2 < IMG_H && gc0 + 2 < IMG_W) {
                // interior: no address bounds checks (kval select only)
                #pragma unroll
                for (int j = 0; j < 8; ++j)
                    fv[j] = kval[j] ? gp[koff[j]] : padf[j];
            } else {
                // edge: full checks (rg==15&rl==1 rows, pc==47 cols)
                #pragma unroll
                for (int j = 0; j < 8; ++j) {
                    float v = padf[j];
                    if (kval[j] && (gr0 + khv[j] < IMG_H) && (gc0 + kwv[j] < IMG_W))
                        v = gp[koff[j]];
                    fv[j] = v;
                }
            }
            uint4_ w4;
            w4.x = __builtin_bit_cast(unsigned int, __builtin_amdgcn_cvt_pkrtz(fv[0], fv[1]));
            w4.y = __builtin_bit_cast(unsigned int, __builtin_amdgcn_cvt_pkrtz(fv[2], fv[3]));
            w4.z = __builtin_bit_cast(unsigned int, __builtin_amdgcn_cvt_pkrtz(fv[4], fv[5]));
            w4.w = __builtin_bit_cast(unsigned int, __builtin_amdgcn_cvt_pkrtz(fv[6], fv[7]));
            int swk = subk ^ ((pl >> 1) & 3);
            *(uint4_*)&sX32[(size_t)(obj * (NPOS * 16) + pl * 16 + swk * 4)] = w4;
        }
    }

    __syncthreads();

    const float4_ zero4 = {0.f, 0.f, 0.f, 0.f};
    const h2 hz = {(__fp16)0.f, (__fp16)0.f};

    float acc[NPAIR];
    #pragma unroll
    for (int q = 0; q < NPAIR; ++q) acc[q] = 0.f;

    #pragma unroll
    for (int nt = 0; nt < 6; ++nt) {    // 2 rows x 3 col-tiles of 16
        const int rl  = nt / 3;
        const int c0  = (nt - rl * 3) * 16;
        const int pos = rl * 48 + c0 + ocl;
        const int sw  = (pos >> 1) & 3;
        const int sbase = pos * 16 + ((quad ^ sw) << 2);

        half8 xf[NOBJ];
        h2 ah01[NOBJ], ah23[NOBJ];
        #pragma unroll
        for (int obj = 0; obj < NOBJ; ++obj) {
            xf[obj] = *(const half8*)&sX32[sbase + obj * (NPOS * 16)];
            float4_ a = __builtin_amdgcn_mfma_f32_16x16x32_f16(wa, xf[obj], zero4, 0, 0, 0);
            ah01[obj] = __builtin_amdgcn_cvt_pkrtz(a[0], a[1]);
            ah23[obj] = __builtin_amdgcn_cvt_pkrtz(a[2], a[3]);
        }

        #pragma unroll
        for (int jo = 0; jo < NOBJ; ++jo) {
            float4_ bq = __builtin_amdgcn_mfma_f32_16x16x32_f16(wb, xf[jo], zero4, 0, 0, 0);
            h2 bh01 = __builtin_amdgcn_cvt_pkrtz(bq[0], bq[1]);
            h2 bh23 = __builtin_amdgcn_cvt_pkrtz(bq[2], bq[3]);
            #pragma unroll
            for (int i = 0; i < NOBJ; ++i) {
                h2 s0 = ah01[i] + bh01;                        // v_pk_add_f16
                h2 s1 = ah23[i] + bh23;
                s0 = __builtin_elementwise_max(s0, hz);        // v_pk_max_f16
                s1 = __builtin_elementwise_max(s1, hz);
                float t0 = __builtin_amdgcn_fdot2(s0, w2h01, acc[i * NOBJ + jo], false);
                acc[i * NOBJ + jo] = __builtin_amdgcn_fdot2(s1, w2h23, t0, false);
            }
        }
    }

    // ---- wave-reduce each pair across 64 lanes; direct store (no atomics) ----
    float myv = 0.f;
    #pragma unroll
    for (int q = 0; q < NPAIR; ++q) {
        float rr = acc[q];
        #pragma unroll
        for (int off = 32; off > 0; off >>= 1)
            rr += __shfl_xor(rr, off, 64);
        if (lane == q) myv = rr;
    }
    if (lane < NPAIR)
        T[((((size_t)src * BQ + b) * NRG + rg) * NPAIR + lane) * 8 + mt] = myv;
}

// predicates: 4 threads per output, each sums 4 rowgroups via float2 loads,
// then a 2-level shfl combine. 51200 threads = 200 blocks.
__global__ __launch_bounds__(256) void pred_kernel(
    const float* __restrict__ T,
    const float* __restrict__ b2,
    const float* __restrict__ temp,
    float* __restrict__ out)
{
    int gid = blockIdx.x * blockDim.x + threadIdx.x;
    int idx = gid >> 2;
    int h   = gid & 3;
    if (idx >= NPRED) return;
    int p   = idx & 3;
    int t   = (idx >> 2) % 1600;
    int src = idx / 6400;
    int bb  = t / NPAIR;
    int pr  = t - bb * NPAIR;
    const float* base = T + ((((size_t)src * BQ + bb) * NRG) * NPAIR + pr) * 8 + 2 * p;
    float sum = 0.f;
    #pragma unroll
    for (int r = 0; r < 4; ++r) {
        int rgi = h * 4 + r;
        float2_ v = *(const float2_*)&base[(size_t)rgi * NPAIR * 8];
        sum += v[0] + v[1];
    }
    sum += __shfl_xor(sum, 1, 64);
    sum += __shfl_xor(sum, 2, 64);
    if (h == 0) {
        float logit = sum * (1.0f / (OH * OW)) + b2[p];
        float x = logit / temp[0];
        out[idx] = 1.0f / (1.0f + expf(-x));
    }
}

extern "C" void kernel_launch(void* const* d_in, const int* in_sizes, int n_in,
                              void* d_out, int out_size, void* d_ws, size_t ws_size,
                              hipStream_t stream)
{
    const float* state      = (const float*)d_in[0];
    const float* state_next = (const float*)d_in[1];
    const float* conv_w     = (const float*)d_in[2];
    const float* conv_b     = (const float*)d_in[3];
    const float* w2         = (const float*)d_in[4];
    const float* b2         = (const float*)d_in[5];
    // d_in[6] = n_obj (always 5)
    const float* temp       = (const float*)d_in[7];

    float* out = (float*)d_out;
    float* T   = (float*)d_ws;              // [2][64][16][25][8] floats = 1.64 MB

    dim3 grid1(NRG, BQ, 2);                 // 2048 blocks x 512 threads
    conv_pair_mfma<<<grid1, 512, 0, stream>>>(state, state_next, conv_w, conv_b,
                                              w2, T, out);

    pred_kernel<<<(NPRED * 4 + 255) / 256, 256, 0, stream>>>(T, b2, temp, out);
}